// Round 1
// baseline (638.397 us; speedup 1.0000x reference)
//
#include <hip/hip_runtime.h>
#include <stdint.h>

typedef unsigned short ushort_t;
typedef __attribute__((ext_vector_type(8))) short short8;
typedef __attribute__((ext_vector_type(4))) float float4v;
typedef __attribute__((ext_vector_type(4))) unsigned short ushort4v;

#define AS1 __attribute__((address_space(1)))
#define AS3 __attribute__((address_space(3)))

// ---- bf16 helpers (manual RNE to avoid header/version differences) ----
static __device__ __forceinline__ ushort_t f2bf(float f) {
    union { float f; unsigned int u; } c; c.f = f;
    unsigned int r = c.u + 0x7FFFu + ((c.u >> 16) & 1u);
    return (ushort_t)(r >> 16);
}
static __device__ __forceinline__ float bf2f(ushort_t h) {
    union { unsigned int u; float f; } c; c.u = ((unsigned int)h) << 16;
    return c.f;
}

// async global->LDS, 16B per lane (global_load_lds_dwordx4)
static __device__ __forceinline__ void gload16(const void* g, void* l) {
    __builtin_amdgcn_global_load_lds((const AS1 unsigned int*)g,
                                     (AS3 unsigned int*)l, 16, 0, 0);
}

// ---------------------------------------------------------------------
// Generic bf16 MFMA GEMM, m97 structure: 128x128 tile, BK=32, 256 thr.
// A: [M, K] row-major (as hi/lo bf16 limb arrays if TERMS==3)
// B: [N, K] row-major ("B^T form", hi/lo if TERMS==3)
// C = A*B^T (+bias[n]); OUT: 0 = fp32, 1 = bf16 hi+lo pair, 2 = bf16
// TERMS==3 computes Ah*Bh + Ah*Bl + Al*Bh (split-precision ~fp32 result)
// ---------------------------------------------------------------------
template<int TERMS, int OUT, bool BIAS>
__global__ __launch_bounds__(256)
void gemm_k(const ushort_t* __restrict__ Ah, const ushort_t* __restrict__ Al,
            const ushort_t* __restrict__ Bh, const ushort_t* __restrict__ Bl,
            const float* __restrict__ bias,
            float* __restrict__ Cf, ushort_t* __restrict__ Ch, ushort_t* __restrict__ Cl,
            int K, int N)
{
    extern __shared__ ushort_t smem[];
    ushort_t* sAh = smem;              // 128*32
    ushort_t* sBh = smem + 4096;
    ushort_t* sAl = smem + 8192;       // only when TERMS==3
    ushort_t* sBl = smem + 12288;

    const int t  = threadIdx.x;
    const int bm = blockIdx.x * 128;
    const int bn = blockIdx.y * 128;

    // staging: thread t covers row t/4 (+64 on round 1), 8 elems at (t%4)*8
    const int  srow = t >> 2;
    const int  skg  = (t & 3) * 8;
    const ushort_t* gAh = Ah + (long)(bm + srow) * K + skg;
    const ushort_t* gBh = Bh + (long)(bn + srow) * K + skg;
    const ushort_t* gAl = (TERMS == 3) ? Al + (long)(bm + srow) * K + skg : nullptr;
    const ushort_t* gBl = (TERMS == 3) ? Bl + (long)(bn + srow) * K + skg : nullptr;
    const long rstep = (long)64 * K;

    const int lane = t & 63;
    const int wv   = t >> 6;
    const int wm   = (wv & 1) * 64;
    const int wn   = (wv >> 1) * 64;
    const int lm   = lane & 15;
    const int q    = lane >> 4;

    float4v acc[4][4];
    #pragma unroll
    for (int i = 0; i < 4; ++i)
        #pragma unroll
        for (int j = 0; j < 4; ++j)
            #pragma unroll
            for (int r = 0; r < 4; ++r) acc[i][j][r] = 0.f;

    for (int kt = 0; kt < K; kt += 32) {
        __syncthreads();
        #pragma unroll
        for (int r = 0; r < 2; ++r) {
            gload16(gAh + kt + r * rstep, sAh + r * 2048 + t * 8);
            gload16(gBh + kt + r * rstep, sBh + r * 2048 + t * 8);
            if (TERMS == 3) {
                gload16(gAl + kt + r * rstep, sAl + r * 2048 + t * 8);
                gload16(gBl + kt + r * rstep, sBl + r * 2048 + t * 8);
            }
        }
        __syncthreads();

        short8 ah[4], bh[4], al[4], bl[4];
        #pragma unroll
        for (int i = 0; i < 4; ++i) {
            ah[i] = *(const short8*)(sAh + (wm + i * 16 + lm) * 32 + q * 8);
            bh[i] = *(const short8*)(sBh + (wn + i * 16 + lm) * 32 + q * 8);
            if (TERMS == 3) {
                al[i] = *(const short8*)(sAl + (wm + i * 16 + lm) * 32 + q * 8);
                bl[i] = *(const short8*)(sBl + (wn + i * 16 + lm) * 32 + q * 8);
            }
        }
        #pragma unroll
        for (int i = 0; i < 4; ++i)
            #pragma unroll
            for (int j = 0; j < 4; ++j) {
                acc[i][j] = __builtin_amdgcn_mfma_f32_16x16x32_bf16(ah[i], bh[j], acc[i][j], 0, 0, 0);
                if (TERMS == 3) {
                    acc[i][j] = __builtin_amdgcn_mfma_f32_16x16x32_bf16(ah[i], bl[j], acc[i][j], 0, 0, 0);
                    acc[i][j] = __builtin_amdgcn_mfma_f32_16x16x32_bf16(al[i], bh[j], acc[i][j], 0, 0, 0);
                }
            }
    }

    // epilogue; C/D layout: col = lane&15, row = (lane>>4)*4 + reg (m89/m91)
    #pragma unroll
    for (int i = 0; i < 4; ++i) {
        const int rowb = bm + wm + i * 16 + q * 4;
        #pragma unroll
        for (int j = 0; j < 4; ++j) {
            const int col = bn + wn + j * 16 + lm;
            const float bv_ = BIAS ? bias[col] : 0.f;
            #pragma unroll
            for (int r = 0; r < 4; ++r) {
                const float val = acc[i][j][r] + bv_;
                const long idx = (long)(rowb + r) * N + col;
                if (OUT == 0) {
                    Cf[idx] = val;
                } else {
                    const ushort_t h = f2bf(val);
                    Ch[idx] = h;
                    if (OUT == 1) Cl[idx] = f2bf(val - bf2f(h));
                }
            }
        }
    }
}

// ---- split fp32 -> bf16 hi/lo limbs (elementwise, float4) ----
__global__ __launch_bounds__(256)
void split_x_k(const float* __restrict__ X, ushort_t* __restrict__ H, ushort_t* __restrict__ L)
{
    const long i = ((long)blockIdx.x * 256 + threadIdx.x) * 4;
    const float4v v = *(const float4v*)(X + i);
    ushort4v h, l;
    #pragma unroll
    for (int j = 0; j < 4; ++j) {
        const ushort_t hh = f2bf(v[j]);
        h[j] = hh;
        l[j] = f2bf(v[j] - bf2f(hh));
    }
    *(ushort4v*)(H + i) = h;
    *(ushort4v*)(L + i) = l;
}

// ---- W [K=1024, N=1024] fp32 -> W^T hi/lo bf16 [N, K] ----
__global__ __launch_bounds__(256)
void transpose_split_w_k(const float* __restrict__ W, ushort_t* __restrict__ WTh, ushort_t* __restrict__ WTl)
{
    __shared__ float tile[64][65];
    const int t  = threadIdx.x;
    const int n0 = blockIdx.x * 64;
    const int k0 = blockIdx.y * 64;
    #pragma unroll
    for (int i = 0; i < 4; ++i) {
        const int r = (t >> 4) + i * 16;     // k local
        const int c = (t & 15) * 4;          // n local
        const float4v v = *(const float4v*)(W + (long)(k0 + r) * 1024 + n0 + c);
        tile[r][c + 0] = v[0]; tile[r][c + 1] = v[1];
        tile[r][c + 2] = v[2]; tile[r][c + 3] = v[3];
    }
    __syncthreads();
    #pragma unroll
    for (int i = 0; i < 4; ++i) {
        const int nr = (t >> 4) + i * 16;    // n local
        const int c  = (t & 15) * 4;         // k local
        ushort4v h, l;
        #pragma unroll
        for (int j = 0; j < 4; ++j) {
            const float f = tile[c + j][nr];
            const ushort_t hh = f2bf(f);
            h[j] = hh;
            l[j] = f2bf(f - bf2f(hh));
        }
        const long off = (long)(n0 + nr) * 1024 + k0 + c;
        *(ushort4v*)(WTh + off) = h;
        *(ushort4v*)(WTl + off) = l;
    }
}

// ---- V bf16 [B*S, D] -> V^T bf16 [B, D, S] ----
__global__ __launch_bounds__(256)
void transpose_v_k(const ushort_t* __restrict__ V, ushort_t* __restrict__ VT)
{
    __shared__ ushort_t tile[64][65];
    const int t  = threadIdx.x;
    const int b  = blockIdx.z;
    const int d0 = blockIdx.x * 64;
    const int s0 = blockIdx.y * 64;
    #pragma unroll
    for (int i = 0; i < 4; ++i) {
        const int r = (t >> 4) + i * 16;     // s local
        const int c = (t & 15) * 4;          // d local
        const ushort4v v = *(const ushort4v*)(V + (long)(b * 2048 + s0 + r) * 1024 + d0 + c);
        tile[r][c + 0] = v[0]; tile[r][c + 1] = v[1];
        tile[r][c + 2] = v[2]; tile[r][c + 3] = v[3];
    }
    __syncthreads();
    #pragma unroll
    for (int i = 0; i < 4; ++i) {
        const int dr = (t >> 4) + i * 16;    // d local
        const int c  = (t & 15) * 4;         // s local
        ushort4v v;
        v[0] = tile[c + 0][dr]; v[1] = tile[c + 1][dr];
        v[2] = tile[c + 2][dr]; v[3] = tile[c + 3][dr];
        *(ushort4v*)(VT + (long)(b * 1024 + d0 + dr) * 2048 + s0 + c) = v;
    }
}

// ---- row softmax: fp32 [rows, 2048] -> bf16 [rows, 2048] ----
__global__ __launch_bounds__(256)
void softmax_k(const float* __restrict__ Sc, ushort_t* __restrict__ P)
{
    const int t = threadIdx.x;
    const long row = blockIdx.x;
    const float4v* src = (const float4v*)(Sc + row * 2048);
    float4v x0 = src[t];
    float4v x1 = src[t + 256];

    float m = -1e30f;
    #pragma unroll
    for (int j = 0; j < 4; ++j) { m = fmaxf(m, x0[j]); m = fmaxf(m, x1[j]); }
    #pragma unroll
    for (int off = 32; off; off >>= 1) m = fmaxf(m, __shfl_xor(m, off, 64));
    __shared__ float r1[4], r2[4];
    if ((t & 63) == 0) r1[t >> 6] = m;
    __syncthreads();
    m = fmaxf(fmaxf(r1[0], r1[1]), fmaxf(r1[2], r1[3]));

    float s = 0.f;
    float4v e0, e1;
    #pragma unroll
    for (int j = 0; j < 4; ++j) {
        e0[j] = __expf(x0[j] - m); s += e0[j];
        e1[j] = __expf(x1[j] - m); s += e1[j];
    }
    #pragma unroll
    for (int off = 32; off; off >>= 1) s += __shfl_xor(s, off, 64);
    if ((t & 63) == 0) r2[t >> 6] = s;
    __syncthreads();
    s = r2[0] + r2[1] + r2[2] + r2[3];
    const float inv = 1.f / s;

    ushort4v p0, p1;
    #pragma unroll
    for (int j = 0; j < 4; ++j) { p0[j] = f2bf(e0[j] * inv); p1[j] = f2bf(e1[j] * inv); }
    ushort4v* dst = (ushort4v*)(P + row * 2048);
    dst[t] = p0;
    dst[t + 256] = p1;
}

// ---------------------------------------------------------------------
extern "C" void kernel_launch(void* const* d_in, const int* in_sizes, int n_in,
                              void* d_out, int out_size, void* d_ws, size_t ws_size,
                              hipStream_t stream)
{
    const float* x  = (const float*)d_in[0];
    const float* Wq = (const float*)d_in[1];
    const float* bq = (const float*)d_in[2];
    const float* Wk = (const float*)d_in[3];
    const float* bk = (const float*)d_in[4];
    const float* Wv = (const float*)d_in[5];
    const float* bv = (const float*)d_in[6];
    float* out = (float*)d_out;

    char* ws = (char*)d_ws;
    const long MB = 1024 * 1024;
    // region A (32MB): xh/xl during projections; scores/attn during attention
    ushort_t* xh     = (ushort_t*)(ws + 0);
    ushort_t* xl     = (ushort_t*)(ws + 16 * MB);
    float*    scores = (float*)   (ws + 0);        // aliases xh/xl (dead then)
    ushort_t* attn   = (ushort_t*)(ws + 16 * MB);
    ushort_t* WqTh = (ushort_t*)(ws + 32 * MB);
    ushort_t* WqTl = (ushort_t*)(ws + 34 * MB);
    ushort_t* WkTh = (ushort_t*)(ws + 36 * MB);
    ushort_t* WkTl = (ushort_t*)(ws + 38 * MB);
    ushort_t* WvTh = (ushort_t*)(ws + 40 * MB);
    ushort_t* WvTl = (ushort_t*)(ws + 42 * MB);
    ushort_t* qh = (ushort_t*)(ws + 44 * MB);
    ushort_t* ql = (ushort_t*)(ws + 60 * MB);
    ushort_t* kh = (ushort_t*)(ws + 76 * MB);
    ushort_t* kl = (ushort_t*)(ws + 92 * MB);
    ushort_t* vv = (ushort_t*)(ws + 108 * MB);
    ushort_t* vT = (ushort_t*)(ws + 124 * MB);     // end: 140 MB

    // 1) split inputs to bf16 hi/lo
    split_x_k<<<8192, 256, 0, stream>>>(x, xh, xl);
    transpose_split_w_k<<<dim3(16, 16), 256, 0, stream>>>(Wq, WqTh, WqTl);
    transpose_split_w_k<<<dim3(16, 16), 256, 0, stream>>>(Wk, WkTh, WkTl);
    transpose_split_w_k<<<dim3(16, 16), 256, 0, stream>>>(Wv, WvTh, WvTl);

    // 2) projections (split-precision): Q,K -> hi/lo bf16; V -> bf16
    dim3 gp(64, 8);
    gemm_k<3, 1, true><<<gp, 256, 32768, stream>>>(xh, xl, WqTh, WqTl, bq, nullptr, qh, ql, 1024, 1024);
    gemm_k<3, 1, true><<<gp, 256, 32768, stream>>>(xh, xl, WkTh, WkTl, bk, nullptr, kh, kl, 1024, 1024);
    gemm_k<3, 2, true><<<gp, 256, 32768, stream>>>(xh, xl, WvTh, WvTl, bv, nullptr, vv, nullptr, 1024, 1024);

    // 3) V -> V^T for the PV GEMM's B^T layout
    transpose_v_k<<<dim3(16, 32, 4), 256, 0, stream>>>(vv, vT);

    // 4) per-batch: scores = QK^T (fp32, split), softmax, out = P V
    for (int b = 0; b < 4; ++b) {
        const long o = (long)b * 2048 * 1024;
        gemm_k<3, 0, false><<<dim3(16, 16), 256, 32768, stream>>>(
            qh + o, ql + o, kh + o, kl + o, nullptr, scores, nullptr, nullptr, 1024, 2048);
        softmax_k<<<2048, 256, 0, stream>>>(scores, attn);
        gemm_k<1, 0, false><<<dim3(16, 8), 256, 16384, stream>>>(
            attn, nullptr, vT + (long)b * 1024 * 2048, nullptr, nullptr, out + o, nullptr, nullptr, 2048, 1024);
    }
}

// Round 2
// 458.022 us; speedup vs baseline: 1.3938x; 1.3938x over previous
//
#include <hip/hip_runtime.h>
#include <stdint.h>

typedef unsigned short ushort_t;
typedef __attribute__((ext_vector_type(8))) short short8;
typedef __attribute__((ext_vector_type(4))) float float4v;
typedef __attribute__((ext_vector_type(4))) unsigned short ushort4v;

#define AS1 __attribute__((address_space(1)))
#define AS3 __attribute__((address_space(3)))

// ---- bf16 helpers (manual RNE) ----
static __device__ __forceinline__ ushort_t f2bf(float f) {
    union { float f; unsigned int u; } c; c.f = f;
    unsigned int r = c.u + 0x7FFFu + ((c.u >> 16) & 1u);
    return (ushort_t)(r >> 16);
}
static __device__ __forceinline__ float bf2f(ushort_t h) {
    union { unsigned int u; float f; } c; c.u = ((unsigned int)h) << 16;
    return c.f;
}

// async global->LDS, 16B per lane (global_load_lds_dwordx4)
static __device__ __forceinline__ void gload16(const void* g, void* l) {
    __builtin_amdgcn_global_load_lds((const AS1 unsigned int*)g,
                                     (AS3 unsigned int*)l, 16, 0, 0);
}

// ---------------------------------------------------------------------
// bf16 MFMA GEMM, m97 structure: 128x128 tile, BK=32, 256 thr, z-batched.
// A: [M, K] rows stride lda (hi/lo limbs if TERMS==3)
// B: [N, K] rows stride ldb ("B^T form", hi/lo if TERMS==3)
// C = A*B^T (+bias[n])
// OUT: 0 = fp32 (ldc), 1 = bf16 hi+lo pair (ldc), 3 = bf16 transposed V
//      (vT[row>>11][col][row&2047], for M=8192 D=1024 S=2048)
// TERMS==3: Ah*Bh + Ah*Bl + Al*Bh (split-precision ~fp32)
// zsA/zsB/zsC: element strides applied per blockIdx.z
// ---------------------------------------------------------------------
template<int TERMS, int OUT, bool BIAS>
__global__ __launch_bounds__(256)
void gemm_k(const ushort_t* __restrict__ Ah, const ushort_t* __restrict__ Al,
            const ushort_t* __restrict__ Bh, const ushort_t* __restrict__ Bl,
            const float* __restrict__ bias,
            float* __restrict__ Cf, ushort_t* __restrict__ Ch, ushort_t* __restrict__ Cl,
            int K, int lda, int ldb, int ldc,
            long zsA, long zsB, long zsC)
{
    extern __shared__ ushort_t smem[];
    ushort_t* sAh = smem;              // 128*32
    ushort_t* sBh = smem + 4096;
    ushort_t* sAl = smem + 8192;       // only when TERMS==3
    ushort_t* sBl = smem + 12288;

    const long zb = blockIdx.z;
    Ah += zb * zsA; Bh += zb * zsB;
    if (TERMS == 3) { Al += zb * zsA; Bl += zb * zsB; }

    const int t  = threadIdx.x;
    const int bm = blockIdx.x * 128;
    const int bn = blockIdx.y * 128;

    const int  srow = t >> 2;
    const int  skg  = (t & 3) * 8;
    const ushort_t* gAh = Ah + (long)(bm + srow) * lda + skg;
    const ushort_t* gBh = Bh + (long)(bn + srow) * ldb + skg;
    const ushort_t* gAl = (TERMS == 3) ? Al + (long)(bm + srow) * lda + skg : nullptr;
    const ushort_t* gBl = (TERMS == 3) ? Bl + (long)(bn + srow) * ldb + skg : nullptr;
    const long rstepA = (long)64 * lda;
    const long rstepB = (long)64 * ldb;

    const int lane = t & 63;
    const int wv   = t >> 6;
    const int wm   = (wv & 1) * 64;
    const int wn   = (wv >> 1) * 64;
    const int lm   = lane & 15;
    const int q    = lane >> 4;

    float4v acc[4][4];
    #pragma unroll
    for (int i = 0; i < 4; ++i)
        #pragma unroll
        for (int j = 0; j < 4; ++j)
            #pragma unroll
            for (int r = 0; r < 4; ++r) acc[i][j][r] = 0.f;

    for (int kt = 0; kt < K; kt += 32) {
        __syncthreads();
        #pragma unroll
        for (int r = 0; r < 2; ++r) {
            gload16(gAh + kt + r * rstepA, sAh + r * 2048 + t * 8);
            gload16(gBh + kt + r * rstepB, sBh + r * 2048 + t * 8);
            if (TERMS == 3) {
                gload16(gAl + kt + r * rstepA, sAl + r * 2048 + t * 8);
                gload16(gBl + kt + r * rstepB, sBl + r * 2048 + t * 8);
            }
        }
        __syncthreads();

        short8 ah[4], bh[4], al[4], bl[4];
        #pragma unroll
        for (int i = 0; i < 4; ++i) {
            ah[i] = *(const short8*)(sAh + (wm + i * 16 + lm) * 32 + q * 8);
            bh[i] = *(const short8*)(sBh + (wn + i * 16 + lm) * 32 + q * 8);
            if (TERMS == 3) {
                al[i] = *(const short8*)(sAl + (wm + i * 16 + lm) * 32 + q * 8);
                bl[i] = *(const short8*)(sBl + (wn + i * 16 + lm) * 32 + q * 8);
            }
        }
        #pragma unroll
        for (int i = 0; i < 4; ++i)
            #pragma unroll
            for (int j = 0; j < 4; ++j) {
                acc[i][j] = __builtin_amdgcn_mfma_f32_16x16x32_bf16(ah[i], bh[j], acc[i][j], 0, 0, 0);
                if (TERMS == 3) {
                    acc[i][j] = __builtin_amdgcn_mfma_f32_16x16x32_bf16(ah[i], bl[j], acc[i][j], 0, 0, 0);
                    acc[i][j] = __builtin_amdgcn_mfma_f32_16x16x32_bf16(al[i], bh[j], acc[i][j], 0, 0, 0);
                }
            }
    }

    // epilogue; C/D layout: col = lane&15, row = (lane>>4)*4 + reg (m89/m91)
    #pragma unroll
    for (int i = 0; i < 4; ++i) {
        const int rowb = bm + wm + i * 16 + q * 4;
        #pragma unroll
        for (int j = 0; j < 4; ++j) {
            const int col = bn + wn + j * 16 + lm;
            const float bv_ = BIAS ? bias[col] : 0.f;
            #pragma unroll
            for (int r = 0; r < 4; ++r) {
                const float val = acc[i][j][r] + bv_;
                const int row = rowb + r;
                if (OUT == 0) {
                    Cf[zb * zsC + (long)row * ldc + col] = val;
                } else if (OUT == 1) {
                    const long idx = zb * zsC + (long)row * ldc + col;
                    const ushort_t h = f2bf(val);
                    Ch[idx] = h;
                    Cl[idx] = f2bf(val - bf2f(h));
                } else { // OUT == 3: vT[b][d][s], b=row>>11, d=col, s=row&2047
                    const long idx = ((long)(row >> 11) * 1024 + col) * 2048 + (row & 2047);
                    Ch[idx] = f2bf(val);
                }
            }
        }
    }
}

// ---- split fp32 -> bf16 hi/lo limbs (elementwise, float4) ----
__global__ __launch_bounds__(256)
void split_x_k(const float* __restrict__ X, ushort_t* __restrict__ H, ushort_t* __restrict__ L)
{
    const long i = ((long)blockIdx.x * 256 + threadIdx.x) * 4;
    const float4v v = *(const float4v*)(X + i);
    ushort4v h, l;
    #pragma unroll
    for (int j = 0; j < 4; ++j) {
        const ushort_t hh = f2bf(v[j]);
        h[j] = hh;
        l[j] = f2bf(v[j] - bf2f(hh));
    }
    *(ushort4v*)(H + i) = h;
    *(ushort4v*)(L + i) = l;
}

// ---- W [K=1024, N=1024] fp32 -> W^T hi(/lo) bf16 [N, K] ----
template<bool LO>
__global__ __launch_bounds__(256)
void transpose_split_w_k(const float* __restrict__ W, ushort_t* __restrict__ WTh, ushort_t* __restrict__ WTl)
{
    __shared__ float tile[64][65];
    const int t  = threadIdx.x;
    const int n0 = blockIdx.x * 64;
    const int k0 = blockIdx.y * 64;
    #pragma unroll
    for (int i = 0; i < 4; ++i) {
        const int r = (t >> 4) + i * 16;     // k local
        const int c = (t & 15) * 4;          // n local
        const float4v v = *(const float4v*)(W + (long)(k0 + r) * 1024 + n0 + c);
        tile[r][c + 0] = v[0]; tile[r][c + 1] = v[1];
        tile[r][c + 2] = v[2]; tile[r][c + 3] = v[3];
    }
    __syncthreads();
    #pragma unroll
    for (int i = 0; i < 4; ++i) {
        const int nr = (t >> 4) + i * 16;    // n local
        const int c  = (t & 15) * 4;         // k local
        ushort4v h, l;
        #pragma unroll
        for (int j = 0; j < 4; ++j) {
            const float f = tile[c + j][nr];
            const ushort_t hh = f2bf(f);
            h[j] = hh;
            if (LO) l[j] = f2bf(f - bf2f(hh));
        }
        const long off = (long)(n0 + nr) * 1024 + k0 + c;
        *(ushort4v*)(WTh + off) = h;
        if (LO) *(ushort4v*)(WTl + off) = l;
    }
}

// ---- concat bq|bk -> bqk[2048] ----
__global__ __launch_bounds__(256)
void bias_concat_k(const float* __restrict__ bq, const float* __restrict__ bk, float* __restrict__ bqk)
{
    const int i = blockIdx.x * 256 + threadIdx.x;
    bqk[i] = (i < 1024) ? bq[i] : bk[i - 1024];
}

// ---- row softmax: fp32 [rows, 2048] -> bf16 [rows, 2048] ----
__global__ __launch_bounds__(256)
void softmax_k(const float* __restrict__ Sc, ushort_t* __restrict__ P)
{
    const int t = threadIdx.x;
    const long row = blockIdx.x;
    const float4v* src = (const float4v*)(Sc + row * 2048);
    float4v x0 = src[t];
    float4v x1 = src[t + 256];

    float m = -1e30f;
    #pragma unroll
    for (int j = 0; j < 4; ++j) { m = fmaxf(m, x0[j]); m = fmaxf(m, x1[j]); }
    #pragma unroll
    for (int off = 32; off; off >>= 1) m = fmaxf(m, __shfl_xor(m, off, 64));
    __shared__ float r1[4], r2[4];
    if ((t & 63) == 0) r1[t >> 6] = m;
    __syncthreads();
    m = fmaxf(fmaxf(r1[0], r1[1]), fmaxf(r1[2], r1[3]));

    float s = 0.f;
    float4v e0, e1;
    #pragma unroll
    for (int j = 0; j < 4; ++j) {
        e0[j] = __expf(x0[j] - m); s += e0[j];
        e1[j] = __expf(x1[j] - m); s += e1[j];
    }
    #pragma unroll
    for (int off = 32; off; off >>= 1) s += __shfl_xor(s, off, 64);
    if ((t & 63) == 0) r2[t >> 6] = s;
    __syncthreads();
    s = r2[0] + r2[1] + r2[2] + r2[3];
    const float inv = 1.f / s;

    ushort4v p0, p1;
    #pragma unroll
    for (int j = 0; j < 4; ++j) { p0[j] = f2bf(e0[j] * inv); p1[j] = f2bf(e1[j] * inv); }
    ushort4v* dst = (ushort4v*)(P + row * 2048);
    dst[t] = p0;
    dst[t + 256] = p1;
}

// ---------------------------------------------------------------------
extern "C" void kernel_launch(void* const* d_in, const int* in_sizes, int n_in,
                              void* d_out, int out_size, void* d_ws, size_t ws_size,
                              hipStream_t stream)
{
    const float* x  = (const float*)d_in[0];
    const float* Wq = (const float*)d_in[1];
    const float* bq = (const float*)d_in[2];
    const float* Wk = (const float*)d_in[3];
    const float* bk = (const float*)d_in[4];
    const float* Wv = (const float*)d_in[5];
    const float* bv = (const float*)d_in[6];
    float* out = (float*)d_out;

    char* ws = (char*)d_ws;
    const long MiB = 1024 * 1024;
    // Phase A: xh/xl + weights; Phase B reuses [0,43) for scores.
    ushort_t* xh     = (ushort_t*)(ws + 0);          // 16 MiB
    ushort_t* xl     = (ushort_t*)(ws + 16 * MiB);   // 16 MiB
    ushort_t* WqkTh  = (ushort_t*)(ws + 32 * MiB);   // 4 MiB [2048,1024]
    ushort_t* WqkTl  = (ushort_t*)(ws + 36 * MiB);   // 4 MiB
    ushort_t* WvTh   = (ushort_t*)(ws + 40 * MiB);   // 2 MiB
    float*    bqk    = (float*)   (ws + 42 * MiB);   // 8 KiB
    ushort_t* qkh    = (ushort_t*)(ws + 43 * MiB);   // 32 MiB [8192,2048]
    ushort_t* qkl    = (ushort_t*)(ws + 75 * MiB);   // 32 MiB
    ushort_t* vT     = (ushort_t*)(ws + 107 * MiB);  // 16 MiB [4][1024][2048]
    float*    scores = (float*)   (ws + 0);          // 32 MiB [2][2048][2048]
    ushort_t* attn   = (ushort_t*)(ws + 123 * MiB);  // 16 MiB [2][2048][2048]
    // total footprint 139 MiB

    // 1) split/transpose inputs
    split_x_k<<<8192, 256, 0, stream>>>(x, xh, xl);
    transpose_split_w_k<true ><<<dim3(16, 16), 256, 0, stream>>>(Wq, WqkTh, WqkTl);
    transpose_split_w_k<true ><<<dim3(16, 16), 256, 0, stream>>>(Wk, WqkTh + 1048576, WqkTl + 1048576);
    transpose_split_w_k<false><<<dim3(16, 16), 256, 0, stream>>>(Wv, WvTh, nullptr);
    bias_concat_k<<<8, 256, 0, stream>>>(bq, bk, bqk);

    // 2) merged Q|K projection (split-precision, hi/lo out), N=2048 -> 1024 blocks
    gemm_k<3, 1, true><<<dim3(64, 16, 1), 256, 32768, stream>>>(
        xh, xl, WqkTh, WqkTl, bqk, nullptr, qkh, qkl,
        1024, 1024, 1024, 2048, 0, 0, 0);

    // 3) V projection (plain bf16), epilogue writes V^T directly
    gemm_k<1, 3, true><<<dim3(64, 8, 1), 256, 16384, stream>>>(
        xh, nullptr, WvTh, nullptr, bv, nullptr, vT, nullptr,
        1024, 1024, 1024, 0, 0, 0, 0);

    // 4) attention in batch-pairs (z=2): scores = QK^T, softmax, out = P V
    for (int p = 0; p < 2; ++p) {
        const long qo = (long)p * 2 * 2048 * 2048;   // qkh/qkl element offset
        gemm_k<3, 0, false><<<dim3(16, 16, 2), 256, 32768, stream>>>(
            qkh + qo, qkl + qo, qkh + qo + 1024, qkl + qo + 1024, nullptr,
            scores, nullptr, nullptr,
            1024, 2048, 2048, 2048,
            (long)2048 * 2048, (long)2048 * 2048, (long)2048 * 2048);
        softmax_k<<<4096, 256, 0, stream>>>(scores, attn);
        gemm_k<1, 0, false><<<dim3(16, 8, 2), 256, 16384, stream>>>(
            attn, nullptr, vT + (long)p * 2 * 1024 * 2048, nullptr, nullptr,
            out + (long)p * 2 * 2048 * 1024, nullptr, nullptr,
            2048, 2048, 2048, 1024,
            (long)2048 * 2048, (long)1024 * 2048, (long)2048 * 1024);
    }
}

// Round 3
// 442.996 us; speedup vs baseline: 1.4411x; 1.0339x over previous
//
#include <hip/hip_runtime.h>
#include <stdint.h>

typedef unsigned short ushort_t;
typedef __attribute__((ext_vector_type(8))) short short8;
typedef __attribute__((ext_vector_type(4))) float float4v;
typedef __attribute__((ext_vector_type(4))) unsigned short ushort4v;

#define AS1 __attribute__((address_space(1)))
#define AS3 __attribute__((address_space(3)))

// ---- bf16 helpers (manual RNE) ----
static __device__ __forceinline__ ushort_t f2bf(float f) {
    union { float f; unsigned int u; } c; c.f = f;
    unsigned int r = c.u + 0x7FFFu + ((c.u >> 16) & 1u);
    return (ushort_t)(r >> 16);
}
static __device__ __forceinline__ float bf2f(ushort_t h) {
    union { unsigned int u; float f; } c; c.u = ((unsigned int)h) << 16;
    return c.f;
}

// async global->LDS, 16B per lane (global_load_lds_dwordx4)
static __device__ __forceinline__ void gload16(const void* g, void* l) {
    __builtin_amdgcn_global_load_lds((const AS1 unsigned int*)g,
                                     (AS3 unsigned int*)l, 16, 0, 0);
}

// ---------------------------------------------------------------------
// bf16 MFMA GEMM, m97 structure: 128x128 tile, BK=32, 256 thr, z-batched.
// A: [M, K] rows stride lda (hi/lo limbs if TERMS==3)
// B: [N, K] rows stride ldb ("B^T form", hi/lo if TERMS==3)
// C = A*B^T (+bias[n])
// OUT: 0 = fp32 (ldc)
//      1 = bf16 hi+lo pair (ldc)
//      4 = QKV fused: col<2048 -> bf16 hi/lo at row*2048+col;
//          col>=2048 -> bf16 V^T at Vt[(row>>11)*1024 + col-2048][row&2047]
//          V-col blocks (bn>=2048) skip the lo-limb terms/staging (1-term).
// TERMS==3: Ah*Bh + Ah*Bl + Al*Bh (split-precision ~fp32)
// zsA/zsB/zsC: element strides applied per blockIdx.z
// ---------------------------------------------------------------------
template<int TERMS, int OUT, bool BIAS>
__global__ __launch_bounds__(256)
void gemm_k(const ushort_t* __restrict__ Ah, const ushort_t* __restrict__ Al,
            const ushort_t* __restrict__ Bh, const ushort_t* __restrict__ Bl,
            const float* __restrict__ bias,
            float* __restrict__ Cf, ushort_t* __restrict__ Ch, ushort_t* __restrict__ Cl,
            ushort_t* __restrict__ Vt,
            int K, int lda, int ldb, int ldc,
            long zsA, long zsB, long zsC)
{
    extern __shared__ ushort_t smem[];
    ushort_t* sAh = smem;              // 128*32
    ushort_t* sBh = smem + 4096;
    ushort_t* sAl = smem + 8192;       // only when lo terms active
    ushort_t* sBl = smem + 12288;

    const long zb = blockIdx.z;
    Ah += zb * zsA; Bh += zb * zsB;
    if (TERMS == 3) { Al += zb * zsA; Bl += zb * zsB; }

    const int t  = threadIdx.x;
    const int bm = blockIdx.x * 128;
    const int bn = blockIdx.y * 128;
    // V-column blocks of the fused QKV projection run 1-term
    const bool lo_on = (TERMS == 3) && (OUT != 4 || bn < 2048);

    const int  srow = t >> 2;
    const int  skg  = (t & 3) * 8;
    const ushort_t* gAh = Ah + (long)(bm + srow) * lda + skg;
    const ushort_t* gBh = Bh + (long)(bn + srow) * ldb + skg;
    const ushort_t* gAl = (TERMS == 3) ? Al + (long)(bm + srow) * lda + skg : nullptr;
    const ushort_t* gBl = (TERMS == 3) ? Bl + (long)(bn + srow) * ldb + skg : nullptr;
    const long rstepA = (long)64 * lda;
    const long rstepB = (long)64 * ldb;

    const int lane = t & 63;
    const int wv   = t >> 6;
    const int wm   = (wv & 1) * 64;
    const int wn   = (wv >> 1) * 64;
    const int lm   = lane & 15;
    const int q    = lane >> 4;

    float4v acc[4][4];
    #pragma unroll
    for (int i = 0; i < 4; ++i)
        #pragma unroll
        for (int j = 0; j < 4; ++j)
            #pragma unroll
            for (int r = 0; r < 4; ++r) acc[i][j][r] = 0.f;

    for (int kt = 0; kt < K; kt += 32) {
        __syncthreads();
        #pragma unroll
        for (int r = 0; r < 2; ++r) {
            gload16(gAh + kt + r * rstepA, sAh + r * 2048 + t * 8);
            gload16(gBh + kt + r * rstepB, sBh + r * 2048 + t * 8);
            if (TERMS == 3) if (lo_on) {
                gload16(gAl + kt + r * rstepA, sAl + r * 2048 + t * 8);
                gload16(gBl + kt + r * rstepB, sBl + r * 2048 + t * 8);
            }
        }
        __syncthreads();

        short8 ah[4], bh[4], al[4], bl[4];
        #pragma unroll
        for (int i = 0; i < 4; ++i) {
            ah[i] = *(const short8*)(sAh + (wm + i * 16 + lm) * 32 + q * 8);
            bh[i] = *(const short8*)(sBh + (wn + i * 16 + lm) * 32 + q * 8);
        }
        if (TERMS == 3) if (lo_on) {
            #pragma unroll
            for (int i = 0; i < 4; ++i) {
                al[i] = *(const short8*)(sAl + (wm + i * 16 + lm) * 32 + q * 8);
                bl[i] = *(const short8*)(sBl + (wn + i * 16 + lm) * 32 + q * 8);
            }
        }
        #pragma unroll
        for (int i = 0; i < 4; ++i)
            #pragma unroll
            for (int j = 0; j < 4; ++j)
                acc[i][j] = __builtin_amdgcn_mfma_f32_16x16x32_bf16(ah[i], bh[j], acc[i][j], 0, 0, 0);
        if (TERMS == 3) if (lo_on) {
            #pragma unroll
            for (int i = 0; i < 4; ++i)
                #pragma unroll
                for (int j = 0; j < 4; ++j) {
                    acc[i][j] = __builtin_amdgcn_mfma_f32_16x16x32_bf16(ah[i], bl[j], acc[i][j], 0, 0, 0);
                    acc[i][j] = __builtin_amdgcn_mfma_f32_16x16x32_bf16(al[i], bh[j], acc[i][j], 0, 0, 0);
                }
        }
    }

    // epilogue; C/D layout: col = lane&15, row = (lane>>4)*4 + reg (m89/m91)
    #pragma unroll
    for (int i = 0; i < 4; ++i) {
        const int rowb = bm + wm + i * 16 + q * 4;
        #pragma unroll
        for (int j = 0; j < 4; ++j) {
            const int col = bn + wn + j * 16 + lm;
            const float bv_ = BIAS ? bias[col] : 0.f;
            if (OUT == 4 && col >= 2048) {
                // packed V^T store: 4 consecutive s-positions -> one 8B store
                ushort4v pk;
                #pragma unroll
                for (int r = 0; r < 4; ++r) pk[r] = f2bf(acc[i][j][r] + bv_);
                const int row = rowb;  // rows rowb..rowb+3 consecutive in s
                *(ushort4v*)(Vt + ((long)(row >> 11) * 1024 + (col - 2048)) * 2048 + (row & 2047)) = pk;
            } else {
                #pragma unroll
                for (int r = 0; r < 4; ++r) {
                    const float val = acc[i][j][r] + bv_;
                    const int row = rowb + r;
                    if (OUT == 0) {
                        Cf[zb * zsC + (long)row * ldc + col] = val;
                    } else { // OUT 1, or OUT 4 with col<2048
                        const long idx = (OUT == 1 ? zb * zsC : 0) + (long)row * ldc + col;
                        const ushort_t h = f2bf(val);
                        Ch[idx] = h;
                        Cl[idx] = f2bf(val - bf2f(h));
                    }
                }
            }
        }
    }
}

// ---- split fp32 -> bf16 hi/lo limbs (elementwise, float4) ----
__global__ __launch_bounds__(256)
void split_x_k(const float* __restrict__ X, ushort_t* __restrict__ H, ushort_t* __restrict__ L)
{
    const long i = ((long)blockIdx.x * 256 + threadIdx.x) * 4;
    const float4v v = *(const float4v*)(X + i);
    ushort4v h, l;
    #pragma unroll
    for (int j = 0; j < 4; ++j) {
        const ushort_t hh = f2bf(v[j]);
        h[j] = hh;
        l[j] = f2bf(v[j] - bf2f(hh));
    }
    *(ushort4v*)(H + i) = h;
    *(ushort4v*)(L + i) = l;
}

// ---- W [1024,1024] fp32 x3 -> W^T hi/lo bf16 [3072,1024]; z picks Wq/Wk/Wv ----
__global__ __launch_bounds__(256)
void transpose_split_w_k(const float* __restrict__ Wq, const float* __restrict__ Wk,
                         const float* __restrict__ Wv,
                         ushort_t* __restrict__ WTh, ushort_t* __restrict__ WTl)
{
    __shared__ float tile[64][65];
    const int z = blockIdx.z;
    const float* W = (z == 0) ? Wq : (z == 1) ? Wk : Wv;
    ushort_t* Th = WTh + (long)z * 1048576;
    ushort_t* Tl = WTl + (long)z * 1048576;
    const bool lo = (z < 2);   // V blocks never read the lo limbs

    const int t  = threadIdx.x;
    const int n0 = blockIdx.x * 64;
    const int k0 = blockIdx.y * 64;
    #pragma unroll
    for (int i = 0; i < 4; ++i) {
        const int r = (t >> 4) + i * 16;     // k local
        const int c = (t & 15) * 4;          // n local
        const float4v v = *(const float4v*)(W + (long)(k0 + r) * 1024 + n0 + c);
        tile[r][c + 0] = v[0]; tile[r][c + 1] = v[1];
        tile[r][c + 2] = v[2]; tile[r][c + 3] = v[3];
    }
    __syncthreads();
    #pragma unroll
    for (int i = 0; i < 4; ++i) {
        const int nr = (t >> 4) + i * 16;    // n local
        const int c  = (t & 15) * 4;         // k local
        ushort4v h, l;
        #pragma unroll
        for (int j = 0; j < 4; ++j) {
            const float f = tile[c + j][nr];
            const ushort_t hh = f2bf(f);
            h[j] = hh;
            l[j] = f2bf(f - bf2f(hh));
        }
        const long off = (long)(n0 + nr) * 1024 + k0 + c;
        *(ushort4v*)(Th + off) = h;
        if (lo) *(ushort4v*)(Tl + off) = l;
    }
}

// ---- concat bq|bk|bv -> bqkv[3072] ----
__global__ __launch_bounds__(256)
void bias_concat_k(const float* __restrict__ bq, const float* __restrict__ bk,
                   const float* __restrict__ bv, float* __restrict__ bqkv)
{
    const int i = blockIdx.x * 256 + threadIdx.x;
    bqkv[i] = (i < 1024) ? bq[i] : (i < 2048) ? bk[i - 1024] : bv[i - 2048];
}

// ---- row softmax: fp32 [rows, 2048] -> bf16 [rows, 2048] ----
__global__ __launch_bounds__(256)
void softmax_k(const float* __restrict__ Sc, ushort_t* __restrict__ P)
{
    const int t = threadIdx.x;
    const long row = blockIdx.x;
    const float4v* src = (const float4v*)(Sc + row * 2048);
    float4v x0 = src[t];
    float4v x1 = src[t + 256];

    float m = -1e30f;
    #pragma unroll
    for (int j = 0; j < 4; ++j) { m = fmaxf(m, x0[j]); m = fmaxf(m, x1[j]); }
    #pragma unroll
    for (int off = 32; off; off >>= 1) m = fmaxf(m, __shfl_xor(m, off, 64));
    __shared__ float r1[4], r2[4];
    if ((t & 63) == 0) r1[t >> 6] = m;
    __syncthreads();
    m = fmaxf(fmaxf(r1[0], r1[1]), fmaxf(r1[2], r1[3]));

    float s = 0.f;
    float4v e0, e1;
    #pragma unroll
    for (int j = 0; j < 4; ++j) {
        e0[j] = __expf(x0[j] - m); s += e0[j];
        e1[j] = __expf(x1[j] - m); s += e1[j];
    }
    #pragma unroll
    for (int off = 32; off; off >>= 1) s += __shfl_xor(s, off, 64);
    if ((t & 63) == 0) r2[t >> 6] = s;
    __syncthreads();
    s = r2[0] + r2[1] + r2[2] + r2[3];
    const float inv = 1.f / s;

    ushort4v p0, p1;
    #pragma unroll
    for (int j = 0; j < 4; ++j) { p0[j] = f2bf(e0[j] * inv); p1[j] = f2bf(e1[j] * inv); }
    ushort4v* dst = (ushort4v*)(P + row * 2048);
    dst[t] = p0;
    dst[t + 256] = p1;
}

// ---------------------------------------------------------------------
extern "C" void kernel_launch(void* const* d_in, const int* in_sizes, int n_in,
                              void* d_out, int out_size, void* d_ws, size_t ws_size,
                              hipStream_t stream)
{
    const float* x  = (const float*)d_in[0];
    const float* Wq = (const float*)d_in[1];
    const float* bq = (const float*)d_in[2];
    const float* Wk = (const float*)d_in[3];
    const float* bk = (const float*)d_in[4];
    const float* Wv = (const float*)d_in[5];
    const float* bv = (const float*)d_in[6];
    float* out = (float*)d_out;

    char* ws = (char*)d_ws;
    const long MiB = 1024 * 1024;
    const bool big = ws_size >= (size_t)(176 * MiB);

    // Phase-1 temporaries (dead before attention phase reuses [0,96))
    ushort_t* xh     = (ushort_t*)(ws + 0);          // 16 MiB
    ushort_t* xl     = (ushort_t*)(ws + 16 * MiB);   // 16 MiB
    ushort_t* WTh    = (ushort_t*)(ws + 32 * MiB);   // 6 MiB [3072,1024]
    ushort_t* WTl    = (ushort_t*)(ws + 38 * MiB);   // 6 MiB
    float*    bqkv   = (float*)   (ws + 44 * MiB);   // 12 KiB
    // Persistent + attention-phase buffers
    ushort_t* qkh    = (ushort_t*)(ws + (big ?  96 : 48) * MiB);  // 32 MiB [8192,2048]
    ushort_t* qkl    = (ushort_t*)(ws + (big ? 128 : 80) * MiB);  // 32 MiB
    ushort_t* vT     = (ushort_t*)(ws + (big ? 160 : 112) * MiB); // 16 MiB [4][1024][2048]
    float*    scores = (float*)   (ws + 0);                        // 64 / 32 MiB
    ushort_t* attn   = (ushort_t*)(ws + (big ? 64 : 32) * MiB);   // 32 / 16 MiB

    // 1) split/transpose inputs (3 dispatches)
    split_x_k<<<8192, 256, 0, stream>>>(x, xh, xl);
    transpose_split_w_k<<<dim3(16, 16, 3), 256, 0, stream>>>(Wq, Wk, Wv, WTh, WTl);
    bias_concat_k<<<12, 256, 0, stream>>>(bq, bk, bv, bqkv);

    // 2) fused QKV projection: Q|K split-precision hi/lo, V 1-term -> V^T
    gemm_k<3, 4, true><<<dim3(64, 24, 1), 256, 32768, stream>>>(
        xh, xl, WTh, WTl, bqkv, nullptr, qkh, qkl, vT,
        1024, 1024, 1024, 2048, 0, 0, 0);

    // 3) attention: scores = QK^T (split), softmax, out = P V
    const long SS = (long)2048 * 2048;
    if (big) {
        gemm_k<3, 0, false><<<dim3(16, 16, 4), 256, 32768, stream>>>(
            qkh, qkl, qkh + 1024, qkl + 1024, nullptr, scores, nullptr, nullptr, nullptr,
            1024, 2048, 2048, 2048, SS, SS, SS);
        softmax_k<<<8192, 256, 0, stream>>>(scores, attn);
        gemm_k<1, 0, false><<<dim3(16, 8, 4), 256, 16384, stream>>>(
            attn, nullptr, vT, nullptr, nullptr, out, nullptr, nullptr, nullptr,
            2048, 2048, 2048, 1024, SS, (long)1024 * 2048, (long)2048 * 1024);
    } else {
        for (int p = 0; p < 2; ++p) {
            const long qo = (long)p * 2 * SS;
            gemm_k<3, 0, false><<<dim3(16, 16, 2), 256, 32768, stream>>>(
                qkh + qo, qkl + qo, qkh + qo + 1024, qkl + qo + 1024, nullptr,
                scores, nullptr, nullptr, nullptr,
                1024, 2048, 2048, 2048, SS, SS, SS);
            softmax_k<<<4096, 256, 0, stream>>>(scores, attn);
            gemm_k<1, 0, false><<<dim3(16, 8, 2), 256, 16384, stream>>>(
                attn, nullptr, vT + (long)p * 2 * 1024 * 2048, nullptr, nullptr,
                out + (long)p * 2 * 2048 * 1024, nullptr, nullptr, nullptr,
                2048, 2048, 2048, 1024, SS, (long)1024 * 2048, (long)2048 * 1024);
        }
    }
}

// Round 4
// 309.751 us; speedup vs baseline: 2.0610x; 1.4302x over previous
//
#include <hip/hip_runtime.h>
#include <stdint.h>

typedef unsigned short ushort_t;
typedef _Float16 f16;
typedef __attribute__((ext_vector_type(8))) _Float16 half8;
typedef __attribute__((ext_vector_type(4))) _Float16 half4;
typedef __attribute__((ext_vector_type(4))) float float4v;

#define AS1 __attribute__((address_space(1)))
#define AS3 __attribute__((address_space(3)))

// async global->LDS, 16B per lane (global_load_lds_dwordx4)
static __device__ __forceinline__ void gload16(const void* g, void* l) {
    __builtin_amdgcn_global_load_lds((const AS1 unsigned int*)g,
                                     (AS3 unsigned int*)l, 16, 0, 0);
}

// ---------------------------------------------------------------------
// fp16 MFMA GEMM, m97 structure: 128x128 tile, BK=32, 256 thr, z-batched.
// A: [M, K] rows stride lda (fp16); B: [N, K] rows stride ldb (fp16)
// C = A*B^T (+bias[n])
// OUT: 0 = fp32 at Cf[z*zsC + row*ldc + col]
//      4 = fused QKV epilogue: col<2048 -> f16 qk[row*2048+col];
//          col>=2048 -> f16 V^T packed: Vt[(row>>11)*1024 + col-2048][row&2047]
// ---------------------------------------------------------------------
template<int OUT, bool BIAS>
__global__ __launch_bounds__(256)
void gemm_k(const f16* __restrict__ A, const f16* __restrict__ B,
            const float* __restrict__ bias,
            float* __restrict__ Cf, f16* __restrict__ Ch, f16* __restrict__ Vt,
            int K, int lda, int ldb, int ldc,
            long zsA, long zsB, long zsC)
{
    extern __shared__ f16 smem[];
    f16* sA = smem;            // 128*32
    f16* sB = smem + 4096;

    const long zb = blockIdx.z;
    A += zb * zsA; B += zb * zsB;

    const int t  = threadIdx.x;
    const int bm = blockIdx.x * 128;
    const int bn = blockIdx.y * 128;

    const int  srow = t >> 2;
    const int  skg  = (t & 3) * 8;
    const f16* gA = A + (long)(bm + srow) * lda + skg;
    const f16* gB = B + (long)(bn + srow) * ldb + skg;
    const long rstepA = (long)64 * lda;
    const long rstepB = (long)64 * ldb;

    const int lane = t & 63;
    const int wv   = t >> 6;
    const int wm   = (wv & 1) * 64;
    const int wn   = (wv >> 1) * 64;
    const int lm   = lane & 15;
    const int q    = lane >> 4;

    float4v acc[4][4];
    #pragma unroll
    for (int i = 0; i < 4; ++i)
        #pragma unroll
        for (int j = 0; j < 4; ++j)
            #pragma unroll
            for (int r = 0; r < 4; ++r) acc[i][j][r] = 0.f;

    for (int kt = 0; kt < K; kt += 32) {
        __syncthreads();
        #pragma unroll
        for (int r = 0; r < 2; ++r) {
            gload16(gA + kt + r * rstepA, sA + r * 2048 + t * 8);
            gload16(gB + kt + r * rstepB, sB + r * 2048 + t * 8);
        }
        __syncthreads();

        half8 a[4], b[4];
        #pragma unroll
        for (int i = 0; i < 4; ++i) {
            a[i] = *(const half8*)(sA + (wm + i * 16 + lm) * 32 + q * 8);
            b[i] = *(const half8*)(sB + (wn + i * 16 + lm) * 32 + q * 8);
        }
        #pragma unroll
        for (int i = 0; i < 4; ++i)
            #pragma unroll
            for (int j = 0; j < 4; ++j)
                acc[i][j] = __builtin_amdgcn_mfma_f32_16x16x32_f16(a[i], b[j], acc[i][j], 0, 0, 0);
    }

    // epilogue; C/D layout: col = lane&15, row = (lane>>4)*4 + reg (m89/m91)
    #pragma unroll
    for (int i = 0; i < 4; ++i) {
        const int rowb = bm + wm + i * 16 + q * 4;
        #pragma unroll
        for (int j = 0; j < 4; ++j) {
            const int col = bn + wn + j * 16 + lm;
            const float bv_ = BIAS ? bias[col] : 0.f;
            if (OUT == 4 && col >= 2048) {
                // packed V^T store: 4 consecutive s-positions -> one 8B store
                half4 pk;
                #pragma unroll
                for (int r = 0; r < 4; ++r) pk[r] = (f16)(acc[i][j][r] + bv_);
                *(half4*)(Vt + ((long)(rowb >> 11) * 1024 + (col - 2048)) * 2048 + (rowb & 2047)) = pk;
            } else {
                #pragma unroll
                for (int r = 0; r < 4; ++r) {
                    const float val = acc[i][j][r] + bv_;
                    const int row = rowb + r;
                    if (OUT == 0) Cf[zb * zsC + (long)row * ldc + col] = val;
                    else          Ch[(long)row * ldc + col] = (f16)val;
                }
            }
        }
    }
}

// ---- fp32 -> fp16 (elementwise, float4) ----
__global__ __launch_bounds__(256)
void convert_x_k(const float* __restrict__ X, f16* __restrict__ H)
{
    const long i = ((long)blockIdx.x * 256 + threadIdx.x) * 4;
    const float4v v = *(const float4v*)(X + i);
    half4 h;
    #pragma unroll
    for (int j = 0; j < 4; ++j) h[j] = (f16)v[j];
    *(half4*)(H + i) = h;
}

// ---- W [1024,1024] fp32 x3 -> W^T fp16 [3072,1024]; z picks Wq/Wk/Wv ----
__global__ __launch_bounds__(256)
void transpose_w_k(const float* __restrict__ Wq, const float* __restrict__ Wk,
                   const float* __restrict__ Wv, f16* __restrict__ WT)
{
    __shared__ float tile[64][65];
    const int z = blockIdx.z;
    const float* W = (z == 0) ? Wq : (z == 1) ? Wk : Wv;
    f16* T = WT + (long)z * 1048576;

    const int t  = threadIdx.x;
    const int n0 = blockIdx.x * 64;
    const int k0 = blockIdx.y * 64;
    #pragma unroll
    for (int i = 0; i < 4; ++i) {
        const int r = (t >> 4) + i * 16;     // k local
        const int c = (t & 15) * 4;          // n local
        const float4v v = *(const float4v*)(W + (long)(k0 + r) * 1024 + n0 + c);
        tile[r][c + 0] = v[0]; tile[r][c + 1] = v[1];
        tile[r][c + 2] = v[2]; tile[r][c + 3] = v[3];
    }
    __syncthreads();
    #pragma unroll
    for (int i = 0; i < 4; ++i) {
        const int nr = (t >> 4) + i * 16;    // n local
        const int c  = (t & 15) * 4;         // k local
        half4 h;
        #pragma unroll
        for (int j = 0; j < 4; ++j) h[j] = (f16)tile[c + j][nr];
        *(half4*)(T + (long)(n0 + nr) * 1024 + k0 + c) = h;
    }
}

// ---- concat bq|bk|bv -> bqkv[3072] ----
__global__ __launch_bounds__(256)
void bias_concat_k(const float* __restrict__ bq, const float* __restrict__ bk,
                   const float* __restrict__ bv, float* __restrict__ bqkv)
{
    const int i = blockIdx.x * 256 + threadIdx.x;
    bqkv[i] = (i < 1024) ? bq[i] : (i < 2048) ? bk[i - 1024] : bv[i - 2048];
}

// ---- row softmax: fp32 [rows, 2048] -> fp16 [rows, 2048] ----
__global__ __launch_bounds__(256)
void softmax_k(const float* __restrict__ Sc, f16* __restrict__ P)
{
    const int t = threadIdx.x;
    const long row = blockIdx.x;
    const float4v* src = (const float4v*)(Sc + row * 2048);
    float4v x0 = src[t];
    float4v x1 = src[t + 256];

    float m = -1e30f;
    #pragma unroll
    for (int j = 0; j < 4; ++j) { m = fmaxf(m, x0[j]); m = fmaxf(m, x1[j]); }
    #pragma unroll
    for (int off = 32; off; off >>= 1) m = fmaxf(m, __shfl_xor(m, off, 64));
    __shared__ float r1[4], r2[4];
    if ((t & 63) == 0) r1[t >> 6] = m;
    __syncthreads();
    m = fmaxf(fmaxf(r1[0], r1[1]), fmaxf(r1[2], r1[3]));

    float s = 0.f;
    float4v e0, e1;
    #pragma unroll
    for (int j = 0; j < 4; ++j) {
        e0[j] = __expf(x0[j] - m); s += e0[j];
        e1[j] = __expf(x1[j] - m); s += e1[j];
    }
    #pragma unroll
    for (int off = 32; off; off >>= 1) s += __shfl_xor(s, off, 64);
    if ((t & 63) == 0) r2[t >> 6] = s;
    __syncthreads();
    s = r2[0] + r2[1] + r2[2] + r2[3];
    const float inv = 1.f / s;

    half4 p0, p1;
    #pragma unroll
    for (int j = 0; j < 4; ++j) { p0[j] = (f16)(e0[j] * inv); p1[j] = (f16)(e1[j] * inv); }
    half4* dst = (half4*)(P + row * 2048);
    dst[t] = p0;
    dst[t + 256] = p1;
}

// ---------------------------------------------------------------------
extern "C" void kernel_launch(void* const* d_in, const int* in_sizes, int n_in,
                              void* d_out, int out_size, void* d_ws, size_t ws_size,
                              hipStream_t stream)
{
    const float* x  = (const float*)d_in[0];
    const float* Wq = (const float*)d_in[1];
    const float* bq = (const float*)d_in[2];
    const float* Wk = (const float*)d_in[3];
    const float* bk = (const float*)d_in[4];
    const float* Wv = (const float*)d_in[5];
    const float* bv = (const float*)d_in[6];
    float* out = (float*)d_out;

    char* ws = (char*)d_ws;
    const long MiB = 1024 * 1024;
    // Phase-1 temporaries (dead once the projection finishes)
    f16*   xh   = (f16*)  (ws + 0);          // 16 MiB [8192,1024]
    f16*   WT   = (f16*)  (ws + 16 * MiB);   //  6 MiB [3072,1024]
    float* bqkv = (float*)(ws + 22 * MiB);   // 12 KiB
    // Persistent / attention-phase
    float* scores = (float*)(ws + 0);        // 64 MiB [4][2048][2048] (reuses xh/WT)
    f16*   qk     = (f16*) (ws + 64 * MiB);  // 32 MiB [8192,2048] (q cols 0..1023, k cols 1024..2047)
    f16*   vT     = (f16*) (ws + 96 * MiB);  // 16 MiB [4][1024][2048]
    f16*   attn   = (f16*) (ws + 112 * MiB); // 32 MiB [4][2048][2048]  -> total 144 MiB

    // 1) convert/transpose inputs
    convert_x_k<<<8192, 256, 0, stream>>>(x, xh);
    transpose_w_k<<<dim3(16, 16, 3), 256, 0, stream>>>(Wq, Wk, Wv, WT);
    bias_concat_k<<<12, 256, 0, stream>>>(bq, bk, bv, bqkv);

    // 2) fused QKV projection (uniform 1-term fp16), V^T written directly
    gemm_k<4, true><<<dim3(64, 24, 1), 256, 16384, stream>>>(
        xh, WT, bqkv, nullptr, qk, vT,
        1024, 1024, 1024, 2048, 0, 0, 0);

    // 3) attention: scores = QK^T, softmax, out = P V   (all z=4)
    const long SS = (long)2048 * 2048;
    gemm_k<0, false><<<dim3(16, 16, 4), 256, 16384, stream>>>(
        qk, qk + 1024, nullptr, scores, nullptr, nullptr,
        1024, 2048, 2048, 2048, SS, SS, SS);
    softmax_k<<<8192, 256, 0, stream>>>(scores, attn);
    gemm_k<0, false><<<dim3(16, 8, 4), 256, 16384, stream>>>(
        attn, vT, nullptr, out, nullptr, nullptr,
        2048, 2048, 2048, 1024, SS, (long)1024 * 2048, (long)2048 * 1024);
}

// Round 5
// 274.482 us; speedup vs baseline: 2.3258x; 1.1285x over previous
//
#include <hip/hip_runtime.h>
#include <stdint.h>

typedef unsigned short ushort_t;
typedef _Float16 f16;
typedef __attribute__((ext_vector_type(8))) _Float16 half8;
typedef __attribute__((ext_vector_type(4))) _Float16 half4;
typedef __attribute__((ext_vector_type(4))) float float4v;

#define AS1 __attribute__((address_space(1)))
#define AS3 __attribute__((address_space(3)))

// async global->LDS, 16B per lane (global_load_lds_dwordx4)
static __device__ __forceinline__ void gload16(const void* g, void* l) {
    __builtin_amdgcn_global_load_lds((const AS1 unsigned int*)g,
                                     (AS3 unsigned int*)l, 16, 0, 0);
}

// ---------------------------------------------------------------------
// fp16 MFMA GEMM: 128x128 tile, BK=64 (two 128x32 sub-tiles per operand,
// halves barrier count vs BK=32 while keeping the conflict-free 32-wide
// LDS layout and global_load_lds lane-contiguity), 256 thr, z-batched.
// A: [M, K] rows stride lda (fp16); B: [N, K] rows stride ldb (fp16)
// C = A*B^T (+bias[n])
// OUT: 0 = fp32 at Cf[z*zsC + row*ldc + col]
//      4 = fused QKV epilogue: col<2048 -> f16 qk[row*2048+col];
//          col>=2048 -> f16 V^T packed: Vt[(row>>11)*1024 + col-2048][row&2047]
// ---------------------------------------------------------------------
template<int OUT, bool BIAS>
__global__ __launch_bounds__(256)
void gemm_k(const f16* __restrict__ A, const f16* __restrict__ B,
            const float* __restrict__ bias,
            float* __restrict__ Cf, f16* __restrict__ Ch, f16* __restrict__ Vt,
            int K, int lda, int ldb, int ldc,
            long zsA, long zsB, long zsC)
{
    extern __shared__ f16 smem[];
    f16* sA0 = smem;            // 128x32 each (4096 halves)
    f16* sA1 = smem + 4096;
    f16* sB0 = smem + 8192;
    f16* sB1 = smem + 12288;    // total 32 KiB

    const long zb = blockIdx.z;
    A += zb * zsA; B += zb * zsB;

    const int t  = threadIdx.x;
    const int bm = blockIdx.x * 128;
    const int bn = blockIdx.y * 128;

    const int  srow = t >> 2;
    const int  skg  = (t & 3) * 8;
    const f16* gA = A + (long)(bm + srow) * lda + skg;
    const f16* gB = B + (long)(bn + srow) * ldb + skg;
    const long rstepA = (long)64 * lda;
    const long rstepB = (long)64 * ldb;

    const int lane = t & 63;
    const int wv   = t >> 6;
    const int wm   = (wv & 1) * 64;
    const int wn   = (wv >> 1) * 64;
    const int lm   = lane & 15;
    const int q    = lane >> 4;

    float4v acc[4][4];
    #pragma unroll
    for (int i = 0; i < 4; ++i)
        #pragma unroll
        for (int j = 0; j < 4; ++j)
            #pragma unroll
            for (int r = 0; r < 4; ++r) acc[i][j][r] = 0.f;

    for (int kt = 0; kt < K; kt += 64) {
        __syncthreads();
        #pragma unroll
        for (int r = 0; r < 2; ++r) {
            gload16(gA + kt      + r * rstepA, sA0 + r * 2048 + t * 8);
            gload16(gA + kt + 32 + r * rstepA, sA1 + r * 2048 + t * 8);
            gload16(gB + kt      + r * rstepB, sB0 + r * 2048 + t * 8);
            gload16(gB + kt + 32 + r * rstepB, sB1 + r * 2048 + t * 8);
        }
        __syncthreads();

        #pragma unroll
        for (int ks = 0; ks < 2; ++ks) {
            const f16* sA = ks ? sA1 : sA0;
            const f16* sB = ks ? sB1 : sB0;
            half8 a[4], b[4];
            #pragma unroll
            for (int i = 0; i < 4; ++i) {
                a[i] = *(const half8*)(sA + (wm + i * 16 + lm) * 32 + q * 8);
                b[i] = *(const half8*)(sB + (wn + i * 16 + lm) * 32 + q * 8);
            }
            #pragma unroll
            for (int i = 0; i < 4; ++i)
                #pragma unroll
                for (int j = 0; j < 4; ++j)
                    acc[i][j] = __builtin_amdgcn_mfma_f32_16x16x32_f16(a[i], b[j], acc[i][j], 0, 0, 0);
        }
    }

    // epilogue; C/D layout: col = lane&15, row = (lane>>4)*4 + reg (m89/m91)
    #pragma unroll
    for (int i = 0; i < 4; ++i) {
        const int rowb = bm + wm + i * 16 + q * 4;
        #pragma unroll
        for (int j = 0; j < 4; ++j) {
            const int col = bn + wn + j * 16 + lm;
            const float bv_ = BIAS ? bias[col] : 0.f;
            if (OUT == 4 && col >= 2048) {
                // packed V^T store: 4 consecutive s-positions -> one 8B store
                half4 pk;
                #pragma unroll
                for (int r = 0; r < 4; ++r) pk[r] = (f16)(acc[i][j][r] + bv_);
                *(half4*)(Vt + ((long)(rowb >> 11) * 1024 + (col - 2048)) * 2048 + (rowb & 2047)) = pk;
            } else {
                #pragma unroll
                for (int r = 0; r < 4; ++r) {
                    const float val = acc[i][j][r] + bv_;
                    const int row = rowb + r;
                    if (OUT == 0) Cf[zb * zsC + (long)row * ldc + col] = val;
                    else          Ch[(long)row * ldc + col] = (f16)val;
                }
            }
        }
    }
}

// ---- fp32 -> fp16 (elementwise, float4) ----
__global__ __launch_bounds__(256)
void convert_x_k(const float* __restrict__ X, f16* __restrict__ H)
{
    const long i = ((long)blockIdx.x * 256 + threadIdx.x) * 4;
    const float4v v = *(const float4v*)(X + i);
    half4 h;
    #pragma unroll
    for (int j = 0; j < 4; ++j) h[j] = (f16)v[j];
    *(half4*)(H + i) = h;
}

// ---- W [1024,1024] fp32 x3 -> W^T fp16 [3072,1024]; z picks Wq/Wk/Wv ----
__global__ __launch_bounds__(256)
void transpose_w_k(const float* __restrict__ Wq, const float* __restrict__ Wk,
                   const float* __restrict__ Wv, f16* __restrict__ WT)
{
    __shared__ float tile[64][65];
    const int z = blockIdx.z;
    const float* W = (z == 0) ? Wq : (z == 1) ? Wk : Wv;
    f16* T = WT + (long)z * 1048576;

    const int t  = threadIdx.x;
    const int n0 = blockIdx.x * 64;
    const int k0 = blockIdx.y * 64;
    #pragma unroll
    for (int i = 0; i < 4; ++i) {
        const int r = (t >> 4) + i * 16;     // k local
        const int c = (t & 15) * 4;          // n local
        const float4v v = *(const float4v*)(W + (long)(k0 + r) * 1024 + n0 + c);
        tile[r][c + 0] = v[0]; tile[r][c + 1] = v[1];
        tile[r][c + 2] = v[2]; tile[r][c + 3] = v[3];
    }
    __syncthreads();
    #pragma unroll
    for (int i = 0; i < 4; ++i) {
        const int nr = (t >> 4) + i * 16;    // n local
        const int c  = (t & 15) * 4;         // k local
        half4 h;
        #pragma unroll
        for (int j = 0; j < 4; ++j) h[j] = (f16)tile[c + j][nr];
        *(half4*)(T + (long)(n0 + nr) * 1024 + k0 + c) = h;
    }
}

// ---- concat bq|bk|bv -> bqkv[3072] ----
__global__ __launch_bounds__(256)
void bias_concat_k(const float* __restrict__ bq, const float* __restrict__ bk,
                   const float* __restrict__ bv, float* __restrict__ bqkv)
{
    const int i = blockIdx.x * 256 + threadIdx.x;
    bqkv[i] = (i < 1024) ? bq[i] : (i < 2048) ? bk[i - 1024] : bv[i - 2048];
}

// ---- row softmax: fp32 [rows, 2048] -> fp16 [rows, 2048] ----
__global__ __launch_bounds__(256)
void softmax_k(const float* __restrict__ Sc, f16* __restrict__ P)
{
    const int t = threadIdx.x;
    const long row = blockIdx.x;
    const float4v* src = (const float4v*)(Sc + row * 2048);
    float4v x0 = src[t];
    float4v x1 = src[t + 256];

    float m = -1e30f;
    #pragma unroll
    for (int j = 0; j < 4; ++j) { m = fmaxf(m, x0[j]); m = fmaxf(m, x1[j]); }
    #pragma unroll
    for (int off = 32; off; off >>= 1) m = fmaxf(m, __shfl_xor(m, off, 64));
    __shared__ float r1[4], r2[4];
    if ((t & 63) == 0) r1[t >> 6] = m;
    __syncthreads();
    m = fmaxf(fmaxf(r1[0], r1[1]), fmaxf(r1[2], r1[3]));

    float s = 0.f;
    float4v e0, e1;
    #pragma unroll
    for (int j = 0; j < 4; ++j) {
        e0[j] = __expf(x0[j] - m); s += e0[j];
        e1[j] = __expf(x1[j] - m); s += e1[j];
    }
    #pragma unroll
    for (int off = 32; off; off >>= 1) s += __shfl_xor(s, off, 64);
    if ((t & 63) == 0) r2[t >> 6] = s;
    __syncthreads();
    s = r2[0] + r2[1] + r2[2] + r2[3];
    const float inv = 1.f / s;

    half4 p0, p1;
    #pragma unroll
    for (int j = 0; j < 4; ++j) { p0[j] = (f16)(e0[j] * inv); p1[j] = (f16)(e1[j] * inv); }
    half4* dst = (half4*)(P + row * 2048);
    dst[t] = p0;
    dst[t + 256] = p1;
}

// ---------------------------------------------------------------------
extern "C" void kernel_launch(void* const* d_in, const int* in_sizes, int n_in,
                              void* d_out, int out_size, void* d_ws, size_t ws_size,
                              hipStream_t stream)
{
    const float* x  = (const float*)d_in[0];
    const float* Wq = (const float*)d_in[1];
    const float* bq = (const float*)d_in[2];
    const float* Wk = (const float*)d_in[3];
    const float* bk = (const float*)d_in[4];
    const float* Wv = (const float*)d_in[5];
    const float* bv = (const float*)d_in[6];
    float* out = (float*)d_out;

    char* ws = (char*)d_ws;
    const long MiB = 1024 * 1024;
    // Phase-1 temporaries (dead once the projection finishes)
    f16*   xh   = (f16*)  (ws + 0);          // 16 MiB [8192,1024]
    f16*   WT   = (f16*)  (ws + 16 * MiB);   //  6 MiB [3072,1024]
    float* bqkv = (float*)(ws + 22 * MiB);   // 12 KiB
    // Persistent / attention-phase
    float* scores = (float*)(ws + 0);        // 64 MiB [4][2048][2048] (reuses xh/WT)
    f16*   qk     = (f16*) (ws + 64 * MiB);  // 32 MiB [8192,2048] (q cols 0..1023, k cols 1024..2047)
    f16*   vT     = (f16*) (ws + 96 * MiB);  // 16 MiB [4][1024][2048]
    f16*   attn   = (f16*) (ws + 112 * MiB); // 32 MiB [4][2048][2048]  -> total 144 MiB

    // 1) convert/transpose inputs
    convert_x_k<<<8192, 256, 0, stream>>>(x, xh);
    transpose_w_k<<<dim3(16, 16, 3), 256, 0, stream>>>(Wq, Wk, Wv, WT);
    bias_concat_k<<<12, 256, 0, stream>>>(bq, bk, bv, bqkv);

    // 2) fused QKV projection (fp16), V^T written directly
    gemm_k<4, true><<<dim3(64, 24, 1), 256, 32768, stream>>>(
        xh, WT, bqkv, nullptr, qk, vT,
        1024, 1024, 1024, 2048, 0, 0, 0);

    // 3) attention: scores = QK^T, softmax, out = P V   (all z=4)
    const long SS = (long)2048 * 2048;
    gemm_k<0, false><<<dim3(16, 16, 4), 256, 32768, stream>>>(
        qk, qk + 1024, nullptr, scores, nullptr, nullptr,
        1024, 2048, 2048, 2048, SS, SS, SS);
    softmax_k<<<8192, 256, 0, stream>>>(scores, attn);
    gemm_k<0, false><<<dim3(16, 8, 4), 256, 32768, stream>>>(
        attn, vT, nullptr, out, nullptr, nullptr,
        2048, 2048, 2048, 1024, SS, (long)1024 * 2048, (long)2048 * 1024);
}